// Round 5
// baseline (616.939 us; speedup 1.0000x reference)
//
#include <hip/hip_runtime.h>
#include <stdint.h>

typedef __attribute__((ext_vector_type(8))) short short8;
typedef __attribute__((ext_vector_type(4))) float floatx4;

__device__ inline unsigned short f2bf(float f) {
    union { float f; unsigned u; } v; v.f = f;
    unsigned u = v.u;
    u += 0x7fffu + ((u >> 16) & 1u);
    return (unsigned short)(u >> 16);
}
__device__ inline unsigned char f2fp8(float f) {  // OCP e4m3 via HW pack (RNE)
    int r = __builtin_amdgcn_cvt_pk_fp8_f32(f, f, 0, false);
    return (unsigned char)(r & 0xff);
}

// ---------- edge dtype detect ----------
__global__ void k_detect(const unsigned* __restrict__ w, int* __restrict__ flag, int nwords) {
    unsigned a = 0;
    for (int i = 1 + 2 * (int)threadIdx.x; i < nwords; i += 512) a |= w[i];
    if (threadIdx.x == 0) *flag = 0;
    __syncthreads();
    if (a) *flag = 1;  // benign race: all writers write 1 (int32 layout)
}

// ---------- remap + coarse bucket histogram (bucket = dst>>9) ----------
__global__ void k_remap_hist(const void* __restrict__ ei_raw, const int* __restrict__ flag,
                             int* __restrict__ src, int* __restrict__ dst,
                             int* __restrict__ bhist, int E, int n, int NB) {
    __shared__ int lh[256];
    int t = threadIdx.x;  // 1024
    if (t < 256) lh[t] = 0;
    __syncthreads();
    int base = blockIdx.x * 4096;
    bool is32 = (*flag != 0);
#pragma unroll
    for (int j = 0; j < 4; j++) {
        int e = base + j * 1024 + t;
        if (e < E) {
            int s, d;
            if (is32) { const int* p = (const int*)ei_raw; s = p[e]; d = p[E + e]; }
            else      { const long long* p = (const long long*)ei_raw; s = (int)p[e]; d = (int)p[E + e]; }
            s = s < 0 ? 0 : (s >= n ? n - 1 : s);
            d = d < 0 ? 0 : (d >= n ? n - 1 : d);
            src[e] = s; dst[e] = d;
            atomicAdd(&lh[d >> 9], 1);
        }
    }
    __syncthreads();
    if (t < NB && lh[t]) atomicAdd(&bhist[t], lh[t]);
}

// ---------- scan bucket hist -> bbase, pcur; row_ptr[N]=E ----------
__global__ void k_offsets(const int* __restrict__ bhist, int* __restrict__ bbase,
                          int* __restrict__ pcur, int* __restrict__ row_ptr,
                          int E, int n, int NB) {
    __shared__ int sc[256], orig[256];
    int t = threadIdx.x;  // 256
    int v = (t < NB) ? bhist[t] : 0;
    orig[t] = v; sc[t] = v;
    __syncthreads();
    for (int off = 1; off < 256; off <<= 1) {
        int x = (t >= off) ? sc[t - off] : 0;
        __syncthreads();
        sc[t] += x;
        __syncthreads();
    }
    if (t < NB) {
        int e = sc[t] - orig[t];
        bbase[t] = e; pcur[t] = e;
    }
    if (t == NB) bbase[t] = E;
    if (t == 0) row_ptr[n] = E;
}

// ---------- phase 1: group edges by coarse bucket (coalesced runs) ----------
__global__ void k_phase1(const int* __restrict__ src, const int* __restrict__ dst,
                         int* __restrict__ pcur, unsigned* __restrict__ pairs, int E, int NB) {
    __shared__ int lh[256];
    __shared__ int gbase[256];
    int t = threadIdx.x;  // 1024
    if (t < 256) lh[t] = 0;
    __syncthreads();
    int base = blockIdx.x * 16384;
    int rank[16], dreg[16];
#pragma unroll
    for (int j = 0; j < 16; j++) {
        int e = base + j * 1024 + t;
        dreg[j] = -1;
        if (e < E) {
            int d = dst[e];
            dreg[j] = d;
            rank[j] = atomicAdd(&lh[d >> 9], 1);
        }
    }
    __syncthreads();
    if (t < NB && lh[t]) gbase[t] = atomicAdd(&pcur[t], lh[t]);
    __syncthreads();
#pragma unroll
    for (int j = 0; j < 16; j++) {
        int e = base + j * 1024 + t;
        if (e < E) {
            int s = src[e];
            int d = dreg[j];
            pairs[gbase[d >> 9] + rank[j]] = ((unsigned)s << 9) | (unsigned)(d & 511);
        }
    }
}

// ---------- phase 2: per-bucket fine sort via LDS; row_ptr/inv_deg inline ----------
__global__ void k_phase2(const unsigned* __restrict__ pairs, const int* __restrict__ bbase,
                         int* __restrict__ row_ptr, float* __restrict__ inv_deg,
                         int* __restrict__ col, int n) {
    __shared__ int lcount[512];
    __shared__ int sc[512];
    __shared__ int lcur[512];
    int t = threadIdx.x;  // 512
    int b = blockIdx.x;
    lcount[t] = 0;
    __syncthreads();
    int e0 = bbase[b], e1 = bbase[b + 1];
    for (int i = e0 + t; i < e1; i += 512) {
        unsigned v = pairs[i];
        atomicAdd(&lcount[v & 511u], 1);
    }
    __syncthreads();
    sc[t] = lcount[t];
    __syncthreads();
    for (int off = 1; off < 512; off <<= 1) {
        int x = (t >= off) ? sc[t - off] : 0;
        __syncthreads();
        sc[t] += x;
        __syncthreads();
    }
    int excl = sc[t] - lcount[t];
    lcur[t] = excl;
    int g = b * 512 + t;
    if (g < n) {
        row_ptr[g] = e0 + excl;
        int c = lcount[t];
        inv_deg[g] = 1.0f / (float)(c > 1 ? c : 1);
    }
    __syncthreads();
    for (int i = e0 + t; i < e1; i += 512) {
        unsigned v = pairs[i];
        int f = v & 511u;
        int p = atomicAdd(&lcur[f], 1);
        col[e0 + p] = (int)(v >> 9);
    }
}

// ---------- weight fragment prep ----------
__global__ void k_w0prep(const float* __restrict__ wl, const float* __restrict__ wr,
                         const float* __restrict__ wn, unsigned short* __restrict__ W0f) {
    int tid = blockIdx.x * 256 + threadIdx.x;  // < 6144
    int lane = tid & 63; int ks = (tid >> 6) & 3; int ct = tid >> 8;
    int o = ct * 16 + (lane & 15);
    int k0 = ks * 32 + (lane >> 4) * 8;
    const float* sp = (o < 128) ? (wl + o * 128)
                    : (o < 256) ? (wr + (o - 128) * 128)
                                : (wn + (o - 256) * 128);
    union { unsigned short u[8]; short8 v; } pk;
#pragma unroll
    for (int j = 0; j < 8; j++) pk.u[j] = f2bf(sp[k0 + j]);
    ((short8*)W0f)[(ct * 4 + ks) * 64 + lane] = pk.v;
}

__global__ void k_w1prep(const float* __restrict__ wpl, const float* __restrict__ wnl,
                         const float* __restrict__ wpr, const float* __restrict__ wnr,
                         unsigned short* __restrict__ W1f) {
    int tid = blockIdx.x * 256 + threadIdx.x;  // < 8192
    int lane = tid & 63; int ks = (tid >> 6) & 7; int ct = tid >> 9;
    int o = ct * 16 + (lane & 15);
    int k0 = ks * 32 + (lane >> 4) * 8;
    union { unsigned short u[8]; short8 v; } pk;
#pragma unroll
    for (int j = 0; j < 8; j++) {
        int k = k0 + j;
        float v;
        if (o < 64)        v = (k < 128) ? wpl[o * 128 + k] : 0.0f;
        else if (o < 128)  v = (k >= 128) ? wnl[(o - 64) * 128 + (k - 128)] : 0.0f;
        else if (o < 192)  v = wpr[(o - 128) * 256 + k];
        else               v = wnr[(o - 192) * 256 + k];
        pk.u[j] = f2bf(v);
    }
    ((short8*)W1f)[(ct * 8 + ks) * 64 + lane] = pk.v;
}

// ---------- GEMM0: [P|Q|R] = x @ [w0_pos_l|w0_pos_r|w0_neg_r].T ----------
// P -> fp8 e4m3 (pre-aggregation); Q/R -> h fp32 (+biases)
__launch_bounds__(256, 2)
__global__ void k_gemm0(const float* __restrict__ x, const unsigned short* __restrict__ W0f,
                        const float* __restrict__ b0p, const float* __restrict__ b0n,
                        unsigned char* __restrict__ P, float* __restrict__ h, int n) {
    __shared__ unsigned short As[64 * 136];
    int t = threadIdx.x; int wave = t >> 6; int lane = t & 63;
    const short8* wf = (const short8*)W0f;
    short8 Bf[6][4];
#pragma unroll
    for (int i = 0; i < 6; i++) {
        int ct = wave * 6 + i;
#pragma unroll
        for (int ks = 0; ks < 4; ks++) Bf[i][ks] = wf[(ct * 4 + ks) * 64 + lane];
    }
    int rowbase = blockIdx.x * 64;
#pragma unroll
    for (int it = 0; it < 4; it++) {
        int seg = it * 256 + t;
        int r = seg >> 4; int k0 = (seg & 15) * 8;
        int row = rowbase + r;
        float4 a = {0, 0, 0, 0}, b = {0, 0, 0, 0};
        if (row < n) {
            a = *(const float4*)(x + (size_t)row * 128 + k0);
            b = *(const float4*)(x + (size_t)row * 128 + k0 + 4);
        }
        union { unsigned short u[8]; uint4 q; } pk;
        pk.u[0] = f2bf(a.x); pk.u[1] = f2bf(a.y); pk.u[2] = f2bf(a.z); pk.u[3] = f2bf(a.w);
        pk.u[4] = f2bf(b.x); pk.u[5] = f2bf(b.y); pk.u[6] = f2bf(b.z); pk.u[7] = f2bf(b.w);
        *(uint4*)(&As[r * 136 + k0]) = pk.q;
    }
    __syncthreads();
    int m = lane & 15; int quad = lane >> 4;
#pragma unroll
    for (int rt = 0; rt < 4; rt++) {
        floatx4 acc[6];
#pragma unroll
        for (int i = 0; i < 6; i++) acc[i] = (floatx4){0.f, 0.f, 0.f, 0.f};
#pragma unroll
        for (int ks = 0; ks < 4; ks++) {
            short8 a = *(const short8*)(&As[(rt * 16 + m) * 136 + ks * 32 + quad * 8]);
#pragma unroll
            for (int i = 0; i < 6; i++)
                acc[i] = __builtin_amdgcn_mfma_f32_16x16x32_bf16(a, Bf[i][ks], acc[i], 0, 0, 0);
        }
#pragma unroll
        for (int i = 0; i < 6; i++) {
            int colg = wave * 96 + i * 16 + m;
            float bias = 0.f;
            if (colg >= 128 && colg < 256) bias = b0p[colg - 128];
            else if (colg >= 256)          bias = b0n[colg - 256];
#pragma unroll
            for (int rr = 0; rr < 4; rr++) {
                int row = rowbase + rt * 16 + quad * 4 + rr;
                if (row < n) {
                    float v = acc[i][rr] + bias;
                    if (colg < 128) P[(size_t)row * 128 + colg] = f2fp8(v);
                    else            h[(size_t)row * 256 + (colg - 128)] = v;
                }
            }
        }
    }
}

// ---------- aggregation: one wave per dst node; split-wave fp8 gather ----------
template<int OSTRIDE>
__global__ __launch_bounds__(256) void k_agg(const int* __restrict__ row_ptr,
                                             const int* __restrict__ col,
                                             const float* __restrict__ inv_deg,
                                             const unsigned* __restrict__ Prow,
                                             float* __restrict__ out, int n) {
    int wid = threadIdx.x >> 6, lane = threadIdx.x & 63;
    int node = blockIdx.x * 4 + wid;
    if (node >= n) return;
    int e0 = row_ptr[node], e1 = row_ptr[node + 1];
    int half = lane >> 5, li = lane & 31;
    float a0 = 0.f, a1 = 0.f, a2 = 0.f, a3 = 0.f;
    for (int j = e0; j < e1; j += 64) {
        int cnt = e1 - j; if (cnt > 64) cnt = 64;
        int idx = j + lane;
        int myc = col[idx < e1 ? idx : e1 - 1];
        int i = 0;
        for (; i + 8 <= cnt; i += 8) {
            int sA = __shfl(myc, i + half);
            int sB = __shfl(myc, i + 2 + half);
            int sC = __shfl(myc, i + 4 + half);
            int sD = __shfl(myc, i + 6 + half);
            unsigned vA = Prow[(size_t)sA * 32 + li];
            unsigned vB = Prow[(size_t)sB * 32 + li];
            unsigned vC = Prow[(size_t)sC * 32 + li];
            unsigned vD = Prow[(size_t)sD * 32 + li];
            a0 += __builtin_amdgcn_cvt_f32_fp8(vA, 0); a1 += __builtin_amdgcn_cvt_f32_fp8(vA, 1);
            a2 += __builtin_amdgcn_cvt_f32_fp8(vA, 2); a3 += __builtin_amdgcn_cvt_f32_fp8(vA, 3);
            a0 += __builtin_amdgcn_cvt_f32_fp8(vB, 0); a1 += __builtin_amdgcn_cvt_f32_fp8(vB, 1);
            a2 += __builtin_amdgcn_cvt_f32_fp8(vB, 2); a3 += __builtin_amdgcn_cvt_f32_fp8(vB, 3);
            a0 += __builtin_amdgcn_cvt_f32_fp8(vC, 0); a1 += __builtin_amdgcn_cvt_f32_fp8(vC, 1);
            a2 += __builtin_amdgcn_cvt_f32_fp8(vC, 2); a3 += __builtin_amdgcn_cvt_f32_fp8(vC, 3);
            a0 += __builtin_amdgcn_cvt_f32_fp8(vD, 0); a1 += __builtin_amdgcn_cvt_f32_fp8(vD, 1);
            a2 += __builtin_amdgcn_cvt_f32_fp8(vD, 2); a3 += __builtin_amdgcn_cvt_f32_fp8(vD, 3);
        }
        for (; i + 2 <= cnt; i += 2) {
            int s = __shfl(myc, i + half);
            unsigned v = Prow[(size_t)s * 32 + li];
            a0 += __builtin_amdgcn_cvt_f32_fp8(v, 0); a1 += __builtin_amdgcn_cvt_f32_fp8(v, 1);
            a2 += __builtin_amdgcn_cvt_f32_fp8(v, 2); a3 += __builtin_amdgcn_cvt_f32_fp8(v, 3);
        }
        if (i < cnt) {
            int s = __shfl(myc, i);  // all lanes participate in the shuffle
            if (half == 0) {
                unsigned v = Prow[(size_t)s * 32 + li];
                a0 += __builtin_amdgcn_cvt_f32_fp8(v, 0); a1 += __builtin_amdgcn_cvt_f32_fp8(v, 1);
                a2 += __builtin_amdgcn_cvt_f32_fp8(v, 2); a3 += __builtin_amdgcn_cvt_f32_fp8(v, 3);
            }
        }
    }
    a0 += __shfl_xor(a0, 32);
    a1 += __shfl_xor(a1, 32);
    a2 += __shfl_xor(a2, 32);
    a3 += __shfl_xor(a3, 32);
    float idg = inv_deg[node];
    float rx = half ? a2 : a0;
    float ry = half ? a3 : a1;
    float* o = out + (size_t)node * OSTRIDE + 4 * li + 2 * half;
    float2 q = *(const float2*)o;
    float2 r;
    r.x = rx * idg + q.x;
    r.y = ry * idg + q.y;
    *(float2*)o = r;
}

// ---------- BN stats: float4 loads, x4 unroll, LDS cross-subgroup reduce ----------
// Grid-stride (multiple of 64 float4s) => each thread owns a fixed column quad.
__global__ __launch_bounds__(256) void k_stats(const float4* __restrict__ hv,
                                               float* __restrict__ colsum,
                                               float* __restrict__ colsumsq, int total4) {
    int t = threadIdx.x;
    int g = blockIdx.x * 256 + t;
    int G = gridDim.x * 256;  // multiple of 64
    float s0 = 0, s1 = 0, s2 = 0, s3 = 0, q0 = 0, q1 = 0, q2 = 0, q3 = 0;
    int i = g;
    for (; i + 3 * G < total4; i += 4 * G) {
        float4 vA = hv[i];
        float4 vB = hv[i + G];
        float4 vC = hv[i + 2 * G];
        float4 vD = hv[i + 3 * G];
        s0 += vA.x; q0 += vA.x * vA.x; s1 += vA.y; q1 += vA.y * vA.y;
        s2 += vA.z; q2 += vA.z * vA.z; s3 += vA.w; q3 += vA.w * vA.w;
        s0 += vB.x; q0 += vB.x * vB.x; s1 += vB.y; q1 += vB.y * vB.y;
        s2 += vB.z; q2 += vB.z * vB.z; s3 += vB.w; q3 += vB.w * vB.w;
        s0 += vC.x; q0 += vC.x * vC.x; s1 += vC.y; q1 += vC.y * vC.y;
        s2 += vC.z; q2 += vC.z * vC.z; s3 += vC.w; q3 += vC.w * vC.w;
        s0 += vD.x; q0 += vD.x * vD.x; s1 += vD.y; q1 += vD.y * vD.y;
        s2 += vD.z; q2 += vD.z * vD.z; s3 += vD.w; q3 += vD.w * vD.w;
    }
    for (; i < total4; i += G) {
        float4 v = hv[i];
        s0 += v.x; q0 += v.x * v.x; s1 += v.y; q1 += v.y * v.y;
        s2 += v.z; q2 += v.z * v.z; s3 += v.w; q3 += v.w * v.w;
    }
    __shared__ float red[256 * 8];
    float* my = &red[t * 8];
    my[0] = s0; my[1] = s1; my[2] = s2; my[3] = s3;
    my[4] = q0; my[5] = q1; my[6] = q2; my[7] = q3;
    __syncthreads();
    if (t < 64) {
        // threads t, t+64, t+128, t+192 share the same column quad (t&63)
#pragma unroll
        for (int j = 0; j < 8; j++)
            red[t * 8 + j] += red[(t + 64) * 8 + j] + red[(t + 128) * 8 + j] + red[(t + 192) * 8 + j];
        int c = t * 4;
        atomicAdd(&colsum[c + 0], red[t * 8 + 0]);
        atomicAdd(&colsum[c + 1], red[t * 8 + 1]);
        atomicAdd(&colsum[c + 2], red[t * 8 + 2]);
        atomicAdd(&colsum[c + 3], red[t * 8 + 3]);
        atomicAdd(&colsumsq[c + 0], red[t * 8 + 4]);
        atomicAdd(&colsumsq[c + 1], red[t * 8 + 5]);
        atomicAdd(&colsumsq[c + 2], red[t * 8 + 6]);
        atomicAdd(&colsumsq[c + 3], red[t * 8 + 7]);
    }
}

__global__ void k_bnfin(const float* __restrict__ colsum, const float* __restrict__ colsumsq,
                        const float* __restrict__ gamma, const float* __restrict__ beta,
                        float* __restrict__ scale, float* __restrict__ shift, int n) {
    int t = threadIdx.x;
    float inv_n = 1.0f / (float)n;
    float mu = colsum[t] * inv_n;
    float var = colsumsq[t] * inv_n - mu * mu;
    float sc = gamma[t] * rsqrtf(var + 1e-5f);
    scale[t] = sc;
    shift[t] = beta[t] - mu * sc;
}

// ---------- GEMM1: fused BN-affine + ReLU + [Y|Z] ----------
__launch_bounds__(256, 2)
__global__ void k_gemm1(const float* __restrict__ h, const unsigned short* __restrict__ W1f,
                        const float* __restrict__ bnscale, const float* __restrict__ bnshift,
                        const float* __restrict__ b1p, const float* __restrict__ b1n,
                        unsigned char* __restrict__ Y, float* __restrict__ out, int n) {
    __shared__ unsigned short As[64 * 264];
    __shared__ float sc[256], sh[256];
    int t = threadIdx.x; int wave = t >> 6; int lane = t & 63;
    sc[t] = bnscale[t]; sh[t] = bnshift[t];
    const short8* wf = (const short8*)W1f;
    short8 Bf[4][8];
#pragma unroll
    for (int i = 0; i < 4; i++) {
        int ct = wave * 4 + i;
#pragma unroll
        for (int ks = 0; ks < 8; ks++) Bf[i][ks] = wf[(ct * 8 + ks) * 64 + lane];
    }
    __syncthreads();
    int rowbase = blockIdx.x * 64;
#pragma unroll
    for (int it = 0; it < 8; it++) {
        int seg = it * 256 + t;
        int r = seg >> 5; int k0 = (seg & 31) * 8;
        int row = rowbase + r;
        union { unsigned short u[8]; uint4 q; } pk;
        if (row < n) {
            float4 a = *(const float4*)(h + (size_t)row * 256 + k0);
            float4 b = *(const float4*)(h + (size_t)row * 256 + k0 + 4);
            float vv[8] = {a.x, a.y, a.z, a.w, b.x, b.y, b.z, b.w};
#pragma unroll
            for (int q2 = 0; q2 < 8; q2++) {
                float v = vv[q2] * sc[k0 + q2] + sh[k0 + q2];
                v = v > 0.f ? v : 0.f;
                pk.u[q2] = f2bf(v);
            }
        } else {
#pragma unroll
            for (int q2 = 0; q2 < 8; q2++) pk.u[q2] = 0;
        }
        *(uint4*)(&As[r * 264 + k0]) = pk.q;
    }
    __syncthreads();
    int m = lane & 15; int quad = lane >> 4;
#pragma unroll
    for (int rt = 0; rt < 4; rt++) {
        floatx4 acc[4];
#pragma unroll
        for (int i = 0; i < 4; i++) acc[i] = (floatx4){0.f, 0.f, 0.f, 0.f};
#pragma unroll
        for (int ks = 0; ks < 8; ks++) {
            short8 a = *(const short8*)(&As[(rt * 16 + m) * 264 + ks * 32 + quad * 8]);
#pragma unroll
            for (int i = 0; i < 4; i++)
                acc[i] = __builtin_amdgcn_mfma_f32_16x16x32_bf16(a, Bf[i][ks], acc[i], 0, 0, 0);
        }
#pragma unroll
        for (int i = 0; i < 4; i++) {
            int colg = wave * 64 + i * 16 + m;
#pragma unroll
            for (int rr = 0; rr < 4; rr++) {
                int row = rowbase + rt * 16 + quad * 4 + rr;
                if (row < n) {
                    float v = acc[i][rr];
                    if (colg < 128) {
                        Y[(size_t)row * 128 + colg] = f2fp8(v);
                    } else {
                        float bias = (colg < 192) ? b1p[colg - 128] : b1n[colg - 192];
                        out[(size_t)row * 128 + (colg - 128)] = v + bias;
                    }
                }
            }
        }
    }
}

extern "C" void kernel_launch(void* const* d_in, const int* in_sizes, int n_in,
                              void* d_out, int out_size, void* d_ws, size_t ws_size,
                              hipStream_t stream) {
    const float* x        = (const float*)d_in[0];
    const void*  ei_raw   = d_in[1];
    const float* w0_pos_l = (const float*)d_in[2];
    const float* w0_pos_r = (const float*)d_in[3];
    const float* b0_pos_r = (const float*)d_in[4];
    const float* w0_neg_r = (const float*)d_in[5];
    const float* b0_neg_r = (const float*)d_in[6];
    const float* bn_gamma = (const float*)d_in[7];
    const float* bn_beta  = (const float*)d_in[8];
    const float* w1_pos_l = (const float*)d_in[9];
    const float* w1_pos_r = (const float*)d_in[10];
    const float* b1_pos_r = (const float*)d_in[11];
    const float* w1_neg_l = (const float*)d_in[12];
    const float* w1_neg_r = (const float*)d_in[13];
    const float* b1_neg_r = (const float*)d_in[14];
    float* out = (float*)d_out;
    int N = in_sizes[0] / 128;
    int E = in_sizes[1] / 2;
    int NB = (N + 511) >> 9;  // coarse buckets of 512 dst nodes

    char* ws = (char*)d_ws;
    size_t off = 0;
    auto carve = [&](size_t bytes) -> char* {
        char* p = ws + off;
        off += (bytes + 255) & ~(size_t)255;
        return p;
    };
    int*      eflag   = (int*)carve(256);
    int*      src     = (int*)carve((size_t)E * 4);
    int*      dst     = (int*)carve((size_t)E * 4);
    int*      bhist   = (int*)carve((size_t)NB * 4);
    int*      bbase   = (int*)carve((size_t)(NB + 1) * 4);
    int*      pcur    = (int*)carve((size_t)NB * 4);
    int*      row_ptr = (int*)carve((size_t)(N + 1) * 4);
    float*    inv_deg = (float*)carve((size_t)N * 4);
    unsigned* pairs   = (unsigned*)carve((size_t)E * 4);
    int*      ecol    = (int*)carve((size_t)E * 4);
    unsigned char* P  = (unsigned char*)carve((size_t)N * 128);
    float* h          = (float*)carve((size_t)N * 256 * 4);
    unsigned char* Yb = (unsigned char*)carve((size_t)N * 128);
    unsigned short* W0f = (unsigned short*)carve(24 * 4 * 64 * 8 * 2);
    unsigned short* W1f = (unsigned short*)carve(16 * 8 * 64 * 8 * 2);
    float* colsum   = (float*)carve(2 * 256 * 4);
    float* colsumsq = colsum + 256;
    float* bnscale  = (float*)carve(256 * 4);
    float* bnshift  = (float*)carve(256 * 4);

    hipMemsetAsync(bhist, 0, (size_t)NB * 4, stream);
    hipMemsetAsync(colsum, 0, 2 * 256 * 4, stream);

    int nwords = 2 * E < 32768 ? 2 * E : 32768;
    k_detect<<<1, 256, 0, stream>>>((const unsigned*)ei_raw, eflag, nwords);
    k_remap_hist<<<(E + 4095) / 4096, 1024, 0, stream>>>(ei_raw, eflag, src, dst, bhist, E, N, NB);
    k_offsets<<<1, 256, 0, stream>>>(bhist, bbase, pcur, row_ptr, E, N, NB);
    k_phase1<<<(E + 16383) / 16384, 1024, 0, stream>>>(src, dst, pcur, pairs, E, NB);
    k_phase2<<<NB, 512, 0, stream>>>(pairs, bbase, row_ptr, inv_deg, ecol, N);

    k_w0prep<<<24, 256, 0, stream>>>(w0_pos_l, w0_pos_r, w0_neg_r, W0f);
    k_w1prep<<<32, 256, 0, stream>>>(w1_pos_l, w1_neg_l, w1_pos_r, w1_neg_r, W1f);

    int gb = (N + 63) / 64;
    k_gemm0<<<gb, 256, 0, stream>>>(x, W0f, b0_pos_r, b0_neg_r, P, h, N);
    k_agg<256><<<(N + 3) / 4, 256, 0, stream>>>(row_ptr, ecol, inv_deg, (const unsigned*)P, h, N);
    k_stats<<<1024, 256, 0, stream>>>((const float4*)h, colsum, colsumsq, N * 64);
    k_bnfin<<<1, 256, 0, stream>>>(colsum, colsumsq, bn_gamma, bn_beta, bnscale, bnshift, N);
    k_gemm1<<<gb, 256, 0, stream>>>(h, W1f, bnscale, bnshift, b1_pos_r, b1_neg_r, Yb, out, N);
    k_agg<128><<<(N + 3) / 4, 256, 0, stream>>>(row_ptr, ecol, inv_deg, (const unsigned*)Yb, out, N);
}

// Round 6
// 564.092 us; speedup vs baseline: 1.0937x; 1.0937x over previous
//
#include <hip/hip_runtime.h>
#include <stdint.h>

typedef __attribute__((ext_vector_type(8))) short short8;
typedef __attribute__((ext_vector_type(4))) float floatx4;

__device__ inline unsigned short f2bf(float f) {
    union { float f; unsigned u; } v; v.f = f;
    unsigned u = v.u;
    u += 0x7fffu + ((u >> 16) & 1u);
    return (unsigned short)(u >> 16);
}
__device__ inline unsigned char f2fp8(float f) {  // OCP e4m3 via HW pack (RNE)
    int r = __builtin_amdgcn_cvt_pk_fp8_f32(f, f, 0, false);
    return (unsigned char)(r & 0xff);
}

// ---------- edge dtype detect ----------
__global__ void k_detect(const unsigned* __restrict__ w, int* __restrict__ flag, int nwords) {
    unsigned a = 0;
    for (int i = 1 + 2 * (int)threadIdx.x; i < nwords; i += 512) a |= w[i];
    if (threadIdx.x == 0) *flag = 0;
    __syncthreads();
    if (a) *flag = 1;  // benign race: all writers write 1 (int32 layout)
}

// ---------- remap + coarse bucket histogram (bucket = dst>>9) ----------
__global__ void k_remap_hist(const void* __restrict__ ei_raw, const int* __restrict__ flag,
                             int* __restrict__ src, int* __restrict__ dst,
                             int* __restrict__ bhist, int E, int n, int NB) {
    __shared__ int lh[256];
    int t = threadIdx.x;  // 1024
    if (t < 256) lh[t] = 0;
    __syncthreads();
    int base = blockIdx.x * 4096;
    bool is32 = (*flag != 0);
#pragma unroll
    for (int j = 0; j < 4; j++) {
        int e = base + j * 1024 + t;
        if (e < E) {
            int s, d;
            if (is32) { const int* p = (const int*)ei_raw; s = p[e]; d = p[E + e]; }
            else      { const long long* p = (const long long*)ei_raw; s = (int)p[e]; d = (int)p[E + e]; }
            s = s < 0 ? 0 : (s >= n ? n - 1 : s);
            d = d < 0 ? 0 : (d >= n ? n - 1 : d);
            src[e] = s; dst[e] = d;
            atomicAdd(&lh[d >> 9], 1);
        }
    }
    __syncthreads();
    if (t < NB && lh[t]) atomicAdd(&bhist[t], lh[t]);
}

// ---------- scan bucket hist -> bbase, pcur; row_ptr[N]=E ----------
__global__ void k_offsets(const int* __restrict__ bhist, int* __restrict__ bbase,
                          int* __restrict__ pcur, int* __restrict__ row_ptr,
                          int E, int n, int NB) {
    __shared__ int sc[256], orig[256];
    int t = threadIdx.x;  // 256
    int v = (t < NB) ? bhist[t] : 0;
    orig[t] = v; sc[t] = v;
    __syncthreads();
    for (int off = 1; off < 256; off <<= 1) {
        int x = (t >= off) ? sc[t - off] : 0;
        __syncthreads();
        sc[t] += x;
        __syncthreads();
    }
    if (t < NB) {
        int e = sc[t] - orig[t];
        bbase[t] = e; pcur[t] = e;
    }
    if (t == NB) bbase[t] = E;
    if (t == 0) row_ptr[n] = E;
}

// ---------- phase 1: group edges by coarse bucket (coalesced runs) ----------
__global__ void k_phase1(const int* __restrict__ src, const int* __restrict__ dst,
                         int* __restrict__ pcur, unsigned* __restrict__ pairs, int E, int NB) {
    __shared__ int lh[256];
    __shared__ int gbase[256];
    int t = threadIdx.x;  // 1024
    if (t < 256) lh[t] = 0;
    __syncthreads();
    int base = blockIdx.x * 16384;
    int rank[16], dreg[16];
#pragma unroll
    for (int j = 0; j < 16; j++) {
        int e = base + j * 1024 + t;
        dreg[j] = -1;
        if (e < E) {
            int d = dst[e];
            dreg[j] = d;
            rank[j] = atomicAdd(&lh[d >> 9], 1);
        }
    }
    __syncthreads();
    if (t < NB && lh[t]) gbase[t] = atomicAdd(&pcur[t], lh[t]);
    __syncthreads();
#pragma unroll
    for (int j = 0; j < 16; j++) {
        int e = base + j * 1024 + t;
        if (e < E) {
            int s = src[e];
            int d = dreg[j];
            pairs[gbase[d >> 9] + rank[j]] = ((unsigned)s << 9) | (unsigned)(d & 511);
        }
    }
}

// ---------- phase 2: per-bucket fine sort via LDS; row_ptr/inv_deg inline ----------
__global__ void k_phase2(const unsigned* __restrict__ pairs, const int* __restrict__ bbase,
                         int* __restrict__ row_ptr, float* __restrict__ inv_deg,
                         int* __restrict__ col, int n) {
    __shared__ int lcount[512];
    __shared__ int sc[512];
    __shared__ int lcur[512];
    int t = threadIdx.x;  // 512
    int b = blockIdx.x;
    lcount[t] = 0;
    __syncthreads();
    int e0 = bbase[b], e1 = bbase[b + 1];
    for (int i = e0 + t; i < e1; i += 512) {
        unsigned v = pairs[i];
        atomicAdd(&lcount[v & 511u], 1);
    }
    __syncthreads();
    sc[t] = lcount[t];
    __syncthreads();
    for (int off = 1; off < 512; off <<= 1) {
        int x = (t >= off) ? sc[t - off] : 0;
        __syncthreads();
        sc[t] += x;
        __syncthreads();
    }
    int excl = sc[t] - lcount[t];
    lcur[t] = excl;
    int g = b * 512 + t;
    if (g < n) {
        row_ptr[g] = e0 + excl;
        int c = lcount[t];
        inv_deg[g] = 1.0f / (float)(c > 1 ? c : 1);
    }
    __syncthreads();
    for (int i = e0 + t; i < e1; i += 512) {
        unsigned v = pairs[i];
        int f = v & 511u;
        int p = atomicAdd(&lcur[f], 1);
        col[e0 + p] = (int)(v >> 9);
    }
}

// ---------- weight fragment prep ----------
__global__ void k_w0prep(const float* __restrict__ wl, const float* __restrict__ wr,
                         const float* __restrict__ wn, unsigned short* __restrict__ W0f) {
    int tid = blockIdx.x * 256 + threadIdx.x;  // < 6144
    int lane = tid & 63; int ks = (tid >> 6) & 3; int ct = tid >> 8;
    int o = ct * 16 + (lane & 15);
    int k0 = ks * 32 + (lane >> 4) * 8;
    const float* sp = (o < 128) ? (wl + o * 128)
                    : (o < 256) ? (wr + (o - 128) * 128)
                                : (wn + (o - 256) * 128);
    union { unsigned short u[8]; short8 v; } pk;
#pragma unroll
    for (int j = 0; j < 8; j++) pk.u[j] = f2bf(sp[k0 + j]);
    ((short8*)W0f)[(ct * 4 + ks) * 64 + lane] = pk.v;
}

__global__ void k_w1prep(const float* __restrict__ wpl, const float* __restrict__ wnl,
                         const float* __restrict__ wpr, const float* __restrict__ wnr,
                         unsigned short* __restrict__ W1f) {
    int tid = blockIdx.x * 256 + threadIdx.x;  // < 8192
    int lane = tid & 63; int ks = (tid >> 6) & 7; int ct = tid >> 9;
    int o = ct * 16 + (lane & 15);
    int k0 = ks * 32 + (lane >> 4) * 8;
    union { unsigned short u[8]; short8 v; } pk;
#pragma unroll
    for (int j = 0; j < 8; j++) {
        int k = k0 + j;
        float v;
        if (o < 64)        v = (k < 128) ? wpl[o * 128 + k] : 0.0f;
        else if (o < 128)  v = (k >= 128) ? wnl[(o - 64) * 128 + (k - 128)] : 0.0f;
        else if (o < 192)  v = wpr[(o - 128) * 256 + k];
        else               v = wnr[(o - 192) * 256 + k];
        pk.u[j] = f2bf(v);
    }
    ((short8*)W1f)[(ct * 8 + ks) * 64 + lane] = pk.v;
}

// ---------- GEMM0: [P|Q|R] = x @ [w0_pos_l|w0_pos_r|w0_neg_r].T ----------
// P -> fp8 e4m3 (pre-aggregation); Q/R -> h fp32 (+biases)
// Fused: column sum/sumsq of the R half (h cols 128..255) -> colsum/colsumsq.
__launch_bounds__(256, 2)
__global__ void k_gemm0(const float* __restrict__ x, const unsigned short* __restrict__ W0f,
                        const float* __restrict__ b0p, const float* __restrict__ b0n,
                        unsigned char* __restrict__ P, float* __restrict__ h,
                        float* __restrict__ colsum, float* __restrict__ colsumsq, int n) {
    __shared__ unsigned short As[64 * 136];
    int t = threadIdx.x; int wave = t >> 6; int lane = t & 63;
    const short8* wf = (const short8*)W0f;
    short8 Bf[6][4];
#pragma unroll
    for (int i = 0; i < 6; i++) {
        int ct = wave * 6 + i;
#pragma unroll
        for (int ks = 0; ks < 4; ks++) Bf[i][ks] = wf[(ct * 4 + ks) * 64 + lane];
    }
    int rowbase = blockIdx.x * 64;
#pragma unroll
    for (int it = 0; it < 4; it++) {
        int seg = it * 256 + t;
        int r = seg >> 4; int k0 = (seg & 15) * 8;
        int row = rowbase + r;
        float4 a = {0, 0, 0, 0}, b = {0, 0, 0, 0};
        if (row < n) {
            a = *(const float4*)(x + (size_t)row * 128 + k0);
            b = *(const float4*)(x + (size_t)row * 128 + k0 + 4);
        }
        union { unsigned short u[8]; uint4 q; } pk;
        pk.u[0] = f2bf(a.x); pk.u[1] = f2bf(a.y); pk.u[2] = f2bf(a.z); pk.u[3] = f2bf(a.w);
        pk.u[4] = f2bf(b.x); pk.u[5] = f2bf(b.y); pk.u[6] = f2bf(b.z); pk.u[7] = f2bf(b.w);
        *(uint4*)(&As[r * 136 + k0]) = pk.q;
    }
    __syncthreads();
    int m = lane & 15; int quad = lane >> 4;
    float cs[6], cq[6];
#pragma unroll
    for (int i = 0; i < 6; i++) { cs[i] = 0.f; cq[i] = 0.f; }
#pragma unroll
    for (int rt = 0; rt < 4; rt++) {
        floatx4 acc[6];
#pragma unroll
        for (int i = 0; i < 6; i++) acc[i] = (floatx4){0.f, 0.f, 0.f, 0.f};
#pragma unroll
        for (int ks = 0; ks < 4; ks++) {
            short8 a = *(const short8*)(&As[(rt * 16 + m) * 136 + ks * 32 + quad * 8]);
#pragma unroll
            for (int i = 0; i < 6; i++)
                acc[i] = __builtin_amdgcn_mfma_f32_16x16x32_bf16(a, Bf[i][ks], acc[i], 0, 0, 0);
        }
#pragma unroll
        for (int i = 0; i < 6; i++) {
            int colg = wave * 96 + i * 16 + m;
            float bias = 0.f;
            if (colg >= 128 && colg < 256) bias = b0p[colg - 128];
            else if (colg >= 256)          bias = b0n[colg - 256];
#pragma unroll
            for (int rr = 0; rr < 4; rr++) {
                int row = rowbase + rt * 16 + quad * 4 + rr;
                if (row < n) {
                    float v = acc[i][rr] + bias;
                    if (colg < 128) {
                        P[(size_t)row * 128 + colg] = f2fp8(v);
                    } else {
                        h[(size_t)row * 256 + (colg - 128)] = v;
                        if (colg >= 256) { cs[i] += v; cq[i] += v * v; }
                    }
                }
            }
        }
    }
#pragma unroll
    for (int i = 0; i < 6; i++) {
        int colg = wave * 96 + i * 16 + m;
        if (colg >= 256) {
            float s = cs[i];
            s += __shfl_xor(s, 16); s += __shfl_xor(s, 32);
            float q = cq[i];
            q += __shfl_xor(q, 16); q += __shfl_xor(q, 32);
            if (quad == 0) {
                atomicAdd(&colsum[colg - 128], s);
                atomicAdd(&colsumsq[colg - 128], q);
            }
        }
    }
}

// ---------- aggregation: grid-strided waves over dst nodes; split-wave fp8 gather ----------
// If STATS: accumulate column sum/sumsq of the FINAL written values (h cols 0..127).
template<int OSTRIDE, bool STATS>
__global__ __launch_bounds__(256) void k_agg(const int* __restrict__ row_ptr,
                                             const int* __restrict__ col,
                                             const float* __restrict__ inv_deg,
                                             const unsigned* __restrict__ Prow,
                                             float* __restrict__ out,
                                             float* __restrict__ colsum,
                                             float* __restrict__ colsumsq, int n) {
    int wid = threadIdx.x >> 6, lane = threadIdx.x & 63;
    int half = lane >> 5, li = lane & 31;
    float sx = 0.f, sy = 0.f, qx = 0.f, qy = 0.f;
    for (int node = blockIdx.x * 4 + wid; node < n; node += gridDim.x * 4) {
        int e0 = row_ptr[node], e1 = row_ptr[node + 1];
        float a0 = 0.f, a1 = 0.f, a2 = 0.f, a3 = 0.f;
        for (int j = e0; j < e1; j += 64) {
            int cnt = e1 - j; if (cnt > 64) cnt = 64;
            int idx = j + lane;
            int myc = col[idx < e1 ? idx : e1 - 1];
            int i = 0;
            for (; i + 8 <= cnt; i += 8) {
                int sA = __shfl(myc, i + half);
                int sB = __shfl(myc, i + 2 + half);
                int sC = __shfl(myc, i + 4 + half);
                int sD = __shfl(myc, i + 6 + half);
                unsigned vA = Prow[(size_t)sA * 32 + li];
                unsigned vB = Prow[(size_t)sB * 32 + li];
                unsigned vC = Prow[(size_t)sC * 32 + li];
                unsigned vD = Prow[(size_t)sD * 32 + li];
                a0 += __builtin_amdgcn_cvt_f32_fp8(vA, 0); a1 += __builtin_amdgcn_cvt_f32_fp8(vA, 1);
                a2 += __builtin_amdgcn_cvt_f32_fp8(vA, 2); a3 += __builtin_amdgcn_cvt_f32_fp8(vA, 3);
                a0 += __builtin_amdgcn_cvt_f32_fp8(vB, 0); a1 += __builtin_amdgcn_cvt_f32_fp8(vB, 1);
                a2 += __builtin_amdgcn_cvt_f32_fp8(vB, 2); a3 += __builtin_amdgcn_cvt_f32_fp8(vB, 3);
                a0 += __builtin_amdgcn_cvt_f32_fp8(vC, 0); a1 += __builtin_amdgcn_cvt_f32_fp8(vC, 1);
                a2 += __builtin_amdgcn_cvt_f32_fp8(vC, 2); a3 += __builtin_amdgcn_cvt_f32_fp8(vC, 3);
                a0 += __builtin_amdgcn_cvt_f32_fp8(vD, 0); a1 += __builtin_amdgcn_cvt_f32_fp8(vD, 1);
                a2 += __builtin_amdgcn_cvt_f32_fp8(vD, 2); a3 += __builtin_amdgcn_cvt_f32_fp8(vD, 3);
            }
            for (; i + 2 <= cnt; i += 2) {
                int s = __shfl(myc, i + half);
                unsigned v = Prow[(size_t)s * 32 + li];
                a0 += __builtin_amdgcn_cvt_f32_fp8(v, 0); a1 += __builtin_amdgcn_cvt_f32_fp8(v, 1);
                a2 += __builtin_amdgcn_cvt_f32_fp8(v, 2); a3 += __builtin_amdgcn_cvt_f32_fp8(v, 3);
            }
            if (i < cnt) {
                int s = __shfl(myc, i);  // all lanes participate in the shuffle
                if (half == 0) {
                    unsigned v = Prow[(size_t)s * 32 + li];
                    a0 += __builtin_amdgcn_cvt_f32_fp8(v, 0); a1 += __builtin_amdgcn_cvt_f32_fp8(v, 1);
                    a2 += __builtin_amdgcn_cvt_f32_fp8(v, 2); a3 += __builtin_amdgcn_cvt_f32_fp8(v, 3);
                }
            }
        }
        a0 += __shfl_xor(a0, 32);
        a1 += __shfl_xor(a1, 32);
        a2 += __shfl_xor(a2, 32);
        a3 += __shfl_xor(a3, 32);
        float idg = inv_deg[node];
        float rx = half ? a2 : a0;
        float ry = half ? a3 : a1;
        float* o = out + (size_t)node * OSTRIDE + 4 * li + 2 * half;
        float2 q = *(const float2*)o;
        float2 r;
        r.x = rx * idg + q.x;
        r.y = ry * idg + q.y;
        *(float2*)o = r;
        if (STATS) { sx += r.x; sy += r.y; qx += r.x * r.x; qy += r.y * r.y; }
    }
    if (STATS) {
        __shared__ float S[4][128], Q[4][128];
        int c0 = 4 * li + 2 * half;
        S[wid][c0] = sx; S[wid][c0 + 1] = sy;
        Q[wid][c0] = qx; Q[wid][c0 + 1] = qy;
        __syncthreads();
        int t = threadIdx.x;
        if (t < 128) {
            atomicAdd(&colsum[t], S[0][t] + S[1][t] + S[2][t] + S[3][t]);
            atomicAdd(&colsumsq[t], Q[0][t] + Q[1][t] + Q[2][t] + Q[3][t]);
        }
    }
}

__global__ void k_bnfin(const float* __restrict__ colsum, const float* __restrict__ colsumsq,
                        const float* __restrict__ gamma, const float* __restrict__ beta,
                        float* __restrict__ scale, float* __restrict__ shift, int n) {
    int t = threadIdx.x;
    float inv_n = 1.0f / (float)n;
    float mu = colsum[t] * inv_n;
    float var = colsumsq[t] * inv_n - mu * mu;
    float sc = gamma[t] * rsqrtf(var + 1e-5f);
    scale[t] = sc;
    shift[t] = beta[t] - mu * sc;
}

// ---------- GEMM1: fused BN-affine + ReLU + [Y|Z] ----------
__launch_bounds__(256, 2)
__global__ void k_gemm1(const float* __restrict__ h, const unsigned short* __restrict__ W1f,
                        const float* __restrict__ bnscale, const float* __restrict__ bnshift,
                        const float* __restrict__ b1p, const float* __restrict__ b1n,
                        unsigned char* __restrict__ Y, float* __restrict__ out, int n) {
    __shared__ unsigned short As[64 * 264];
    __shared__ float sc[256], sh[256];
    int t = threadIdx.x; int wave = t >> 6; int lane = t & 63;
    sc[t] = bnscale[t]; sh[t] = bnshift[t];
    const short8* wf = (const short8*)W1f;
    short8 Bf[4][8];
#pragma unroll
    for (int i = 0; i < 4; i++) {
        int ct = wave * 4 + i;
#pragma unroll
        for (int ks = 0; ks < 8; ks++) Bf[i][ks] = wf[(ct * 8 + ks) * 64 + lane];
    }
    __syncthreads();
    int rowbase = blockIdx.x * 64;
#pragma unroll
    for (int it = 0; it < 8; it++) {
        int seg = it * 256 + t;
        int r = seg >> 5; int k0 = (seg & 31) * 8;
        int row = rowbase + r;
        union { unsigned short u[8]; uint4 q; } pk;
        if (row < n) {
            float4 a = *(const float4*)(h + (size_t)row * 256 + k0);
            float4 b = *(const float4*)(h + (size_t)row * 256 + k0 + 4);
            float vv[8] = {a.x, a.y, a.z, a.w, b.x, b.y, b.z, b.w};
#pragma unroll
            for (int q2 = 0; q2 < 8; q2++) {
                float v = vv[q2] * sc[k0 + q2] + sh[k0 + q2];
                v = v > 0.f ? v : 0.f;
                pk.u[q2] = f2bf(v);
            }
        } else {
#pragma unroll
            for (int q2 = 0; q2 < 8; q2++) pk.u[q2] = 0;
        }
        *(uint4*)(&As[r * 264 + k0]) = pk.q;
    }
    __syncthreads();
    int m = lane & 15; int quad = lane >> 4;
#pragma unroll
    for (int rt = 0; rt < 4; rt++) {
        floatx4 acc[4];
#pragma unroll
        for (int i = 0; i < 4; i++) acc[i] = (floatx4){0.f, 0.f, 0.f, 0.f};
#pragma unroll
        for (int ks = 0; ks < 8; ks++) {
            short8 a = *(const short8*)(&As[(rt * 16 + m) * 264 + ks * 32 + quad * 8]);
#pragma unroll
            for (int i = 0; i < 4; i++)
                acc[i] = __builtin_amdgcn_mfma_f32_16x16x32_bf16(a, Bf[i][ks], acc[i], 0, 0, 0);
        }
#pragma unroll
        for (int i = 0; i < 4; i++) {
            int colg = wave * 64 + i * 16 + m;
#pragma unroll
            for (int rr = 0; rr < 4; rr++) {
                int row = rowbase + rt * 16 + quad * 4 + rr;
                if (row < n) {
                    float v = acc[i][rr];
                    if (colg < 128) {
                        Y[(size_t)row * 128 + colg] = f2fp8(v);
                    } else {
                        float bias = (colg < 192) ? b1p[colg - 128] : b1n[colg - 192];
                        out[(size_t)row * 128 + (colg - 128)] = v + bias;
                    }
                }
            }
        }
    }
}

extern "C" void kernel_launch(void* const* d_in, const int* in_sizes, int n_in,
                              void* d_out, int out_size, void* d_ws, size_t ws_size,
                              hipStream_t stream) {
    const float* x        = (const float*)d_in[0];
    const void*  ei_raw   = d_in[1];
    const float* w0_pos_l = (const float*)d_in[2];
    const float* w0_pos_r = (const float*)d_in[3];
    const float* b0_pos_r = (const float*)d_in[4];
    const float* w0_neg_r = (const float*)d_in[5];
    const float* b0_neg_r = (const float*)d_in[6];
    const float* bn_gamma = (const float*)d_in[7];
    const float* bn_beta  = (const float*)d_in[8];
    const float* w1_pos_l = (const float*)d_in[9];
    const float* w1_pos_r = (const float*)d_in[10];
    const float* b1_pos_r = (const float*)d_in[11];
    const float* w1_neg_l = (const float*)d_in[12];
    const float* w1_neg_r = (const float*)d_in[13];
    const float* b1_neg_r = (const float*)d_in[14];
    float* out = (float*)d_out;
    int N = in_sizes[0] / 128;
    int E = in_sizes[1] / 2;
    int NB = (N + 511) >> 9;  // coarse buckets of 512 dst nodes

    char* ws = (char*)d_ws;
    size_t off = 0;
    auto carve = [&](size_t bytes) -> char* {
        char* p = ws + off;
        off += (bytes + 255) & ~(size_t)255;
        return p;
    };
    int*      eflag   = (int*)carve(256);
    int*      src     = (int*)carve((size_t)E * 4);
    int*      dst     = (int*)carve((size_t)E * 4);
    int*      bhist   = (int*)carve((size_t)NB * 4);
    int*      bbase   = (int*)carve((size_t)(NB + 1) * 4);
    int*      pcur    = (int*)carve((size_t)NB * 4);
    int*      row_ptr = (int*)carve((size_t)(N + 1) * 4);
    float*    inv_deg = (float*)carve((size_t)N * 4);
    unsigned* pairs   = (unsigned*)carve((size_t)E * 4);
    int*      ecol    = (int*)carve((size_t)E * 4);
    unsigned char* P  = (unsigned char*)carve((size_t)N * 128);
    float* h          = (float*)carve((size_t)N * 256 * 4);
    unsigned char* Yb = (unsigned char*)carve((size_t)N * 128);
    unsigned short* W0f = (unsigned short*)carve(24 * 4 * 64 * 8 * 2);
    unsigned short* W1f = (unsigned short*)carve(16 * 8 * 64 * 8 * 2);
    float* colsum   = (float*)carve(2 * 256 * 4);
    float* colsumsq = colsum + 256;
    float* bnscale  = (float*)carve(256 * 4);
    float* bnshift  = (float*)carve(256 * 4);

    hipMemsetAsync(bhist, 0, (size_t)NB * 4, stream);
    hipMemsetAsync(colsum, 0, 2 * 256 * 4, stream);

    int nwords = 2 * E < 32768 ? 2 * E : 32768;
    k_detect<<<1, 256, 0, stream>>>((const unsigned*)ei_raw, eflag, nwords);
    k_remap_hist<<<(E + 4095) / 4096, 1024, 0, stream>>>(ei_raw, eflag, src, dst, bhist, E, N, NB);
    k_offsets<<<1, 256, 0, stream>>>(bhist, bbase, pcur, row_ptr, E, N, NB);
    k_phase1<<<(E + 16383) / 16384, 1024, 0, stream>>>(src, dst, pcur, pairs, E, NB);
    k_phase2<<<NB, 512, 0, stream>>>(pairs, bbase, row_ptr, inv_deg, ecol, N);

    k_w0prep<<<24, 256, 0, stream>>>(w0_pos_l, w0_pos_r, w0_neg_r, W0f);
    k_w1prep<<<32, 256, 0, stream>>>(w1_pos_l, w1_neg_l, w1_pos_r, w1_neg_r, W1f);

    int gb = (N + 63) / 64;
    k_gemm0<<<gb, 256, 0, stream>>>(x, W0f, b0_pos_r, b0_neg_r, P, h, colsum, colsumsq, N);
    k_agg<256, true><<<2048, 256, 0, stream>>>(row_ptr, ecol, inv_deg, (const unsigned*)P, h,
                                               colsum, colsumsq, N);
    k_bnfin<<<1, 256, 0, stream>>>(colsum, colsumsq, bn_gamma, bn_beta, bnscale, bnshift, N);
    k_gemm1<<<gb, 256, 0, stream>>>(h, W1f, bnscale, bnshift, b1_pos_r, b1_neg_r, Yb, out, N);
    k_agg<128, false><<<2048, 256, 0, stream>>>(row_ptr, ecol, inv_deg, (const unsigned*)Yb, out,
                                                nullptr, nullptr, N);
}